// Round 7
// baseline (93.035 us; speedup 1.0000x reference)
//
#include <hip/hip_runtime.h>

#define HW 262144            // 512*512
#define TSIZE 524288         // 2^19
#define HMASK 524287u
#define PRIME2 2654435761u

// Reference model (R1-R6 A/B): graded ref = JAX/XLA f32 execution. XLA's
// algebraic simplifier rewrites x / const -> x * fl32(1/const) at compile
// time. So all ops f32, with:
//   hx = int32(fl32(cx*n))                       (plain f32 mul + trunc)
//   bx = floorf(fl32(cx * r)), r = fl32(1/inv32) (reciprocal-MULTIPLY, not div)
// Evidence: R5==R6 bit-identical => dominant error was hx => ref hx is f32;
// R1 (f32 hx + f32 DIV bx) still failed => ref bx is not IEEE f32 division.
// NS[15]=127 (proven by R1/R2 max-algebra, three times).
__global__ __launch_bounds__(256)
void hashenc2d_kernel(const float* __restrict__ coord,
                      const float* __restrict__ table,
                      float* __restrict__ out)
{
    constexpr int NS[16] = {8, 9, 11, 13, 16, 20, 24, 29, 35, 42, 50, 61, 73, 88, 106, 127};

    const int g   = blockIdx.x * 256 + threadIdx.x;   // 0 .. 262143
    const int b   = g >> 16;                          // batch
    const int pos = (g & 65535) << 2;                 // 4 consecutive pixels

    const float* cbase = coord + (size_t)b * (2 * HW);
    const float4 cx4 = *reinterpret_cast<const float4*>(cbase + pos);
    const float4 cy4 = *reinterpret_cast<const float4*>(cbase + HW + pos);
    const float cxa[4] = {cx4.x, cx4.y, cx4.z, cx4.w};
    const float cya[4] = {cy4.x, cy4.y, cy4.z, cy4.w};

    float* outb = out + (size_t)b * (32 * HW) + pos;

    #pragma unroll
    for (int l = 0; l < 16; ++l) {
        const float n   = (float)NS[l];
        const float inv = 1.0f / n;     // fl32(1/n), compile-time IEEE fold
        const float rcp = 1.0f / inv;   // fl32(1/inv) = XLA's folded reciprocal
        const float2* __restrict__ tab =
            reinterpret_cast<const float2*>(table) + (size_t)l * TSIZE;

        float o0[4], o1[4];
        #pragma unroll
        for (int p = 0; p < 4; ++p) {
            const float cx = cxa[p];
            const float cy = cya[p];

            // hash cell: f32 mul + trunc (matches XLA)
            const int hx = (int)(cx * n);
            const int hy = (int)(cy * n);
            // weight cell: floor of RECIPROCAL-MULTIPLY product (XLA div rewrite)
            const float bx = floorf(cx * rcp);
            const float by = floorf(cy * rcp);

            const unsigned hyp0 = (unsigned)hy * PRIME2;
            const unsigned hyp1 = (unsigned)(hy + 1) * PRIME2;
            const unsigned i00 = ((unsigned)hx       ^ hyp0) & HMASK;
            const unsigned i10 = ((unsigned)(hx + 1) ^ hyp0) & HMASK;
            const unsigned i01 = ((unsigned)hx       ^ hyp1) & HMASK;
            const unsigned i11 = ((unsigned)(hx + 1) ^ hyp1) & HMASK;

            const float2 f00 = tab[i00];
            const float2 f10 = tab[i10];
            const float2 f01 = tab[i01];
            const float2 f11 = tab[i11];

            const float wx_lo = ((bx + 1.0f) * inv - cx) * n;
            const float wx_hi = (cx - bx * inv) * n;
            const float wy_lo = ((by + 1.0f) * inv - cy) * n;
            const float wy_hi = (cy - by * inv) * n;

            const float r1x = f00.x * wx_lo + f10.x * wx_hi;
            const float r1y = f00.y * wx_lo + f10.y * wx_hi;
            const float r2x = f01.x * wx_lo + f11.x * wx_hi;
            const float r2y = f01.y * wx_lo + f11.y * wx_hi;

            o0[p] = r1x * wy_lo + r2x * wy_hi;
            o1[p] = r1y * wy_lo + r2y * wy_hi;
        }

        *reinterpret_cast<float4*>(outb + (size_t)(2 * l)     * HW) =
            make_float4(o0[0], o0[1], o0[2], o0[3]);
        *reinterpret_cast<float4*>(outb + (size_t)(2 * l + 1) * HW) =
            make_float4(o1[0], o1[1], o1[2], o1[3]);
    }
}

extern "C" void kernel_launch(void* const* d_in, const int* in_sizes, int n_in,
                              void* d_out, int out_size, void* d_ws, size_t ws_size,
                              hipStream_t stream) {
    // coord = 2,097,152 elems; hash_table = 16,777,216 — select by size.
    const float* coord = (const float*)d_in[0];
    const float* table = (const float*)d_in[1];
    if (n_in >= 2 && in_sizes[0] > in_sizes[1]) {
        coord = (const float*)d_in[1];
        table = (const float*)d_in[0];
    }
    float* out = (float*)d_out;

    hashenc2d_kernel<<<1024, 256, 0, stream>>>(coord, table, out);
}

// Round 8
// 69.894 us; speedup vs baseline: 1.3311x; 1.3311x over previous
//
#include <hip/hip_runtime.h>

#define HW 262144            // 512*512
#define TSIZE 524288         // 2^19 entries per level
#define HMASK 524287u
#define PRIME2 2654435761u
#define NLEV_LDS 10          // levels 0..9 staged in LDS (n <= 42)
#define LDS_TOT 6365         // sum of (NS[l]+2)^2 for l<10, in float2

// Reference semantics (locked by R1-R7 A/B): JAX/XLA f32 execution.
//   hx = int32(fl32(cx*n))
//   bx = floorf(fl32(cx * rcp)), rcp = fl32(1/fl32(1/n))  [XLA div->recip-mul]
//   NS[15] = 127 (int(8*b**15) truncates below 128 in f64)
// R7: 93us, VALUBusy 14%, HBM 18% => L1 gather-throughput bound
// (~1 unique line probe/cy/CU). This round: de-hashed dense LDS grids for
// levels 0..9 — replaces 41M global probes with 3.3M staging probes.
__global__ __launch_bounds__(512)
void hashenc2d_kernel(const float* __restrict__ coord,
                      const float* __restrict__ table,
                      float* __restrict__ out)
{
    constexpr int NS[16] = {8, 9, 11, 13, 16, 20, 24, 29, 35, 42, 50, 61, 73, 88, 106, 127};
    // W = NS+2 covers hx+1 <= n+1 (fl32(cx*n) can round up to exactly n).
    constexpr int OFF[10] = {0, 100, 221, 390, 615, 939, 1423, 2099, 3060, 4429};

    __shared__ float2 smem[LDS_TOT];   // 50,920 B

    const float2* __restrict__ tab2 = reinterpret_cast<const float2*>(table);

    // ---- stage levels 0..9 as dense (n+2)^2 grids (de-hashed) ----
    #pragma unroll
    for (int l = 0; l < NLEV_LDS; ++l) {
        const int W  = NS[l] + 2;
        const int SZ = W * W;
        const float2* __restrict__ tabl = tab2 + (size_t)l * TSIZE;
        for (int e = threadIdx.x; e < SZ; e += 512) {
            const int j = e / W;              // const W after unroll -> magic mul
            const int i = e - j * W;
            const unsigned idx = ((unsigned)i ^ ((unsigned)j * PRIME2)) & HMASK;
            smem[OFF[l] + e] = tabl[idx];
        }
    }

    // ---- per-thread pixel quad ----
    const int g   = blockIdx.x * 512 + threadIdx.x;   // 0 .. 262143
    const int P   = g << 2;                           // first of 4 pixels (flat)
    const int b   = P >> 18;                          // batch (HW = 2^18)
    const int pos = P & (HW - 1);

    const float* cbase = coord + (size_t)b * (2 * HW);
    const float4 cx4 = *reinterpret_cast<const float4*>(cbase + pos);
    const float4 cy4 = *reinterpret_cast<const float4*>(cbase + HW + pos);
    const float cxa[4] = {cx4.x, cx4.y, cx4.z, cx4.w};
    const float cya[4] = {cy4.x, cy4.y, cy4.z, cy4.w};

    float* outb = out + (size_t)b * (32 * HW) + pos;

    // ---- direct levels 10..15 BEFORE the barrier (no LDS dependency;
    //      their gathers overlap the staging latency) ----
    #pragma unroll
    for (int l = NLEV_LDS; l < 16; ++l) {
        const float n   = (float)NS[l];
        const float inv = 1.0f / n;
        const float rcp = 1.0f / inv;
        const float2* __restrict__ tabl = tab2 + (size_t)l * TSIZE;

        float o0[4], o1[4];
        #pragma unroll
        for (int p = 0; p < 4; ++p) {
            const float cx = cxa[p], cy = cya[p];
            const int hx = (int)(cx * n);
            const int hy = (int)(cy * n);
            const float bx = floorf(cx * rcp);
            const float by = floorf(cy * rcp);

            const unsigned hyp0 = (unsigned)hy * PRIME2;
            const unsigned hyp1 = (unsigned)(hy + 1) * PRIME2;
            const float2 f00 = tabl[((unsigned)hx       ^ hyp0) & HMASK];
            const float2 f10 = tabl[((unsigned)(hx + 1) ^ hyp0) & HMASK];
            const float2 f01 = tabl[((unsigned)hx       ^ hyp1) & HMASK];
            const float2 f11 = tabl[((unsigned)(hx + 1) ^ hyp1) & HMASK];

            const float wx_lo = ((bx + 1.0f) * inv - cx) * n;
            const float wx_hi = (cx - bx * inv) * n;
            const float wy_lo = ((by + 1.0f) * inv - cy) * n;
            const float wy_hi = (cy - by * inv) * n;

            const float r1x = f00.x * wx_lo + f10.x * wx_hi;
            const float r1y = f00.y * wx_lo + f10.y * wx_hi;
            const float r2x = f01.x * wx_lo + f11.x * wx_hi;
            const float r2y = f01.y * wx_lo + f11.y * wx_hi;
            o0[p] = r1x * wy_lo + r2x * wy_hi;
            o1[p] = r1y * wy_lo + r2y * wy_hi;
        }
        *reinterpret_cast<float4*>(outb + (size_t)(2 * l)     * HW) =
            make_float4(o0[0], o0[1], o0[2], o0[3]);
        *reinterpret_cast<float4*>(outb + (size_t)(2 * l + 1) * HW) =
            make_float4(o1[0], o1[1], o1[2], o1[3]);
    }

    __syncthreads();

    // ---- staged levels 0..9 from LDS ----
    #pragma unroll
    for (int l = 0; l < NLEV_LDS; ++l) {
        const float n   = (float)NS[l];
        const float inv = 1.0f / n;
        const float rcp = 1.0f / inv;
        const int   W   = NS[l] + 2;
        const float2* __restrict__ sl = smem + OFF[l];

        float o0[4], o1[4];
        #pragma unroll
        for (int p = 0; p < 4; ++p) {
            const float cx = cxa[p], cy = cya[p];
            const int hx = (int)(cx * n);
            const int hy = (int)(cy * n);
            const float bx = floorf(cx * rcp);
            const float by = floorf(cy * rcp);

            const int base = hy * W + hx;
            const float2 f00 = sl[base];
            const float2 f10 = sl[base + 1];
            const float2 f01 = sl[base + W];
            const float2 f11 = sl[base + W + 1];

            const float wx_lo = ((bx + 1.0f) * inv - cx) * n;
            const float wx_hi = (cx - bx * inv) * n;
            const float wy_lo = ((by + 1.0f) * inv - cy) * n;
            const float wy_hi = (cy - by * inv) * n;

            const float r1x = f00.x * wx_lo + f10.x * wx_hi;
            const float r1y = f00.y * wx_lo + f10.y * wx_hi;
            const float r2x = f01.x * wx_lo + f11.x * wx_hi;
            const float r2y = f01.y * wx_lo + f11.y * wx_hi;
            o0[p] = r1x * wy_lo + r2x * wy_hi;
            o1[p] = r1y * wy_lo + r2y * wy_hi;
        }
        *reinterpret_cast<float4*>(outb + (size_t)(2 * l)     * HW) =
            make_float4(o0[0], o0[1], o0[2], o0[3]);
        *reinterpret_cast<float4*>(outb + (size_t)(2 * l + 1) * HW) =
            make_float4(o1[0], o1[1], o1[2], o1[3]);
    }
}

extern "C" void kernel_launch(void* const* d_in, const int* in_sizes, int n_in,
                              void* d_out, int out_size, void* d_ws, size_t ws_size,
                              hipStream_t stream) {
    const float* coord = (const float*)d_in[0];
    const float* table = (const float*)d_in[1];
    if (n_in >= 2 && in_sizes[0] > in_sizes[1]) {   // size-based disambiguation
        coord = (const float*)d_in[1];
        table = (const float*)d_in[0];
    }
    float* out = (float*)d_out;

    // 1M pixels / (512 threads * 4 px) = 512 blocks
    hashenc2d_kernel<<<512, 512, 0, stream>>>(coord, table, out);
}

// Round 9
// 67.445 us; speedup vs baseline: 1.3794x; 1.0363x over previous
//
#include <hip/hip_runtime.h>

#define HW 262144            // 512*512
#define TSIZE 524288         // 2^19 entries per level
#define HMASK 524287u
#define PRIME2 2654435761u
#define NLEV_LDS 12          // levels 0..11 staged in LDS (n <= 61)
#define LDS_TOT 13038        // sum of (NS[l]+2)^2 for l<12, in float2 (104,304 B)
#define BLK 1024

// Reference semantics (locked by R1-R7 A/B): JAX/XLA f32 execution.
//   hx = int32(fl32(cx*n))
//   bx = floorf(fl32(cx * rcp)), rcp = fl32(1/fl32(1/n))  [XLA div->recip-mul]
//   NS[15] = 127
// R7: 93us (L1 gather-bound, 67M probes). R8: 70us (levels 0..9 LDS-staged,
// 27M probes). R9: stage levels 10..11 too (dynamic LDS 104KB, 1024-thr
// blocks) -> ~19M probes, predict ~50us.
__global__ __launch_bounds__(BLK)
void hashenc2d_kernel(const float* __restrict__ coord,
                      const float* __restrict__ table,
                      float* __restrict__ out)
{
    constexpr int NS[16] = {8, 9, 11, 13, 16, 20, 24, 29, 35, 42, 50, 61, 73, 88, 106, 127};
    // OFF[l] = cumulative (NS+2)^2 for staged levels
    constexpr int OFF[12] = {0, 100, 221, 390, 615, 939, 1423, 2099, 3060, 4429, 6365, 9069};

    extern __shared__ float2 smem[];   // 13038 float2 = 104,304 B (dynamic)

    const float2* __restrict__ tab2 = reinterpret_cast<const float2*>(table);

    // ---- stage levels 0..11 as dense (n+2)^2 de-hashed grids ----
    #pragma unroll
    for (int l = 0; l < NLEV_LDS; ++l) {
        const int W  = NS[l] + 2;
        const int SZ = W * W;
        const float2* __restrict__ tabl = tab2 + (size_t)l * TSIZE;
        for (int e = threadIdx.x; e < SZ; e += BLK) {
            const int j = e / W;              // W is constexpr after unroll
            const int i = e - j * W;
            const unsigned idx = ((unsigned)i ^ ((unsigned)j * PRIME2)) & HMASK;
            smem[OFF[l] + e] = tabl[idx];
        }
    }

    // ---- per-thread pixel quad ----
    const int g   = blockIdx.x * BLK + threadIdx.x;   // 0 .. 262143
    const int P   = g << 2;                           // first of 4 pixels
    const int b   = P >> 18;                          // batch (HW = 2^18)
    const int pos = P & (HW - 1);

    const float* cbase = coord + (size_t)b * (2 * HW);
    const float4 cx4 = *reinterpret_cast<const float4*>(cbase + pos);
    const float4 cy4 = *reinterpret_cast<const float4*>(cbase + HW + pos);
    const float cxa[4] = {cx4.x, cx4.y, cx4.z, cx4.w};
    const float cya[4] = {cy4.x, cy4.y, cy4.z, cy4.w};

    float* outb = out + (size_t)b * (32 * HW) + pos;

    // ---- direct levels 12..15 BEFORE the barrier (overlap with staging) ----
    #pragma unroll
    for (int l = NLEV_LDS; l < 16; ++l) {
        const float n   = (float)NS[l];
        const float inv = 1.0f / n;
        const float rcp = 1.0f / inv;
        const float2* __restrict__ tabl = tab2 + (size_t)l * TSIZE;

        float o0[4], o1[4];
        #pragma unroll
        for (int p = 0; p < 4; ++p) {
            const float cx = cxa[p], cy = cya[p];
            const int hx = (int)(cx * n);
            const int hy = (int)(cy * n);
            const float bx = floorf(cx * rcp);
            const float by = floorf(cy * rcp);

            const unsigned hyp0 = (unsigned)hy * PRIME2;
            const unsigned hyp1 = (unsigned)(hy + 1) * PRIME2;
            const float2 f00 = tabl[((unsigned)hx       ^ hyp0) & HMASK];
            const float2 f10 = tabl[((unsigned)(hx + 1) ^ hyp0) & HMASK];
            const float2 f01 = tabl[((unsigned)hx       ^ hyp1) & HMASK];
            const float2 f11 = tabl[((unsigned)(hx + 1) ^ hyp1) & HMASK];

            const float wx_lo = ((bx + 1.0f) * inv - cx) * n;
            const float wx_hi = (cx - bx * inv) * n;
            const float wy_lo = ((by + 1.0f) * inv - cy) * n;
            const float wy_hi = (cy - by * inv) * n;

            const float r1x = f00.x * wx_lo + f10.x * wx_hi;
            const float r1y = f00.y * wx_lo + f10.y * wx_hi;
            const float r2x = f01.x * wx_lo + f11.x * wx_hi;
            const float r2y = f01.y * wx_lo + f11.y * wx_hi;
            o0[p] = r1x * wy_lo + r2x * wy_hi;
            o1[p] = r1y * wy_lo + r2y * wy_hi;
        }
        *reinterpret_cast<float4*>(outb + (size_t)(2 * l)     * HW) =
            make_float4(o0[0], o0[1], o0[2], o0[3]);
        *reinterpret_cast<float4*>(outb + (size_t)(2 * l + 1) * HW) =
            make_float4(o1[0], o1[1], o1[2], o1[3]);
    }

    __syncthreads();

    // ---- staged levels 0..11 from LDS ----
    #pragma unroll
    for (int l = 0; l < NLEV_LDS; ++l) {
        const float n   = (float)NS[l];
        const float inv = 1.0f / n;
        const float rcp = 1.0f / inv;
        const int   W   = NS[l] + 2;
        const float2* __restrict__ sl = smem + OFF[l];

        float o0[4], o1[4];
        #pragma unroll
        for (int p = 0; p < 4; ++p) {
            const float cx = cxa[p], cy = cya[p];
            const int hx = (int)(cx * n);
            const int hy = (int)(cy * n);
            const float bx = floorf(cx * rcp);
            const float by = floorf(cy * rcp);

            const int base = hy * W + hx;
            const float2 f00 = sl[base];
            const float2 f10 = sl[base + 1];
            const float2 f01 = sl[base + W];
            const float2 f11 = sl[base + W + 1];

            const float wx_lo = ((bx + 1.0f) * inv - cx) * n;
            const float wx_hi = (cx - bx * inv) * n;
            const float wy_lo = ((by + 1.0f) * inv - cy) * n;
            const float wy_hi = (cy - by * inv) * n;

            const float r1x = f00.x * wx_lo + f10.x * wx_hi;
            const float r1y = f00.y * wx_lo + f10.y * wx_hi;
            const float r2x = f01.x * wx_lo + f11.x * wx_hi;
            const float r2y = f01.y * wx_lo + f11.y * wx_hi;
            o0[p] = r1x * wy_lo + r2x * wy_hi;
            o1[p] = r1y * wy_lo + r2y * wy_hi;
        }
        *reinterpret_cast<float4*>(outb + (size_t)(2 * l)     * HW) =
            make_float4(o0[0], o0[1], o0[2], o0[3]);
        *reinterpret_cast<float4*>(outb + (size_t)(2 * l + 1) * HW) =
            make_float4(o1[0], o1[1], o1[2], o1[3]);
    }
}

extern "C" void kernel_launch(void* const* d_in, const int* in_sizes, int n_in,
                              void* d_out, int out_size, void* d_ws, size_t ws_size,
                              hipStream_t stream) {
    const float* coord = (const float*)d_in[0];
    const float* table = (const float*)d_in[1];
    if (n_in >= 2 && in_sizes[0] > in_sizes[1]) {   // size-based disambiguation
        coord = (const float*)d_in[1];
        table = (const float*)d_in[0];
    }
    float* out = (float*)d_out;

    // 104,304 B dynamic LDS > 64KB static cap: opt in (idempotent, host-side,
    // not a stream op -> graph-capture safe).
    static int lds_bytes = (int)(LDS_TOT * sizeof(float2));
    (void)hipFuncSetAttribute((const void*)hashenc2d_kernel,
                              hipFuncAttributeMaxDynamicSharedMemorySize,
                              lds_bytes);

    // 1M pixels / (1024 threads * 4 px) = 256 blocks
    hashenc2d_kernel<<<256, BLK, LDS_TOT * sizeof(float2), stream>>>(coord, table, out);
}

// Round 10
// 57.690 us; speedup vs baseline: 1.6127x; 1.1691x over previous
//
#include <hip/hip_runtime.h>

#define HW 262144            // 512*512
#define TSIZE 524288         // 2^19 entries per level
#define HMASK 524287u
#define PRIME2 2654435761u
#define NLEV_LDS 13          // levels 0..12 staged (n <= 73)
#define LDS_TOT 18663        // sum of (NS[l]+2)^2 for l<13, float2 = 149,304 B
#define BLKB 1024

typedef float f4 __attribute__((ext_vector_type(4)));

// Reference semantics (locked R1-R7): JAX/XLA f32:
//   hx = int32(fl32(cx*n)); bx = floorf(fl32(cx*rcp)), rcp = fl32(1/fl32(1/n));
//   NS[15] = 127.
// R7 93us (all direct) -> R8 70us (10 staged) -> R9 67us (12 staged, 1 blk/CU).
// R10: two kernels. A: levels 13-15 direct, no LDS, high occupancy.
//      B: levels 0-12 staged (149.3KB LDS). NT stores keep writes out of L2.

__global__ __launch_bounds__(256)
void hashenc_direct(const float* __restrict__ coord,
                    const float* __restrict__ table,
                    float* __restrict__ out)
{
    constexpr int NS3[3] = {88, 106, 127};   // levels 13,14,15

    const int g   = blockIdx.x * 256 + threadIdx.x;   // 0..262143
    const int P   = g << 2;
    const int b   = P >> 18;
    const int pos = P & (HW - 1);

    const float* cbase = coord + (size_t)b * (2 * HW);
    const float4 cx4 = *reinterpret_cast<const float4*>(cbase + pos);
    const float4 cy4 = *reinterpret_cast<const float4*>(cbase + HW + pos);
    const float cxa[4] = {cx4.x, cx4.y, cx4.z, cx4.w};
    const float cya[4] = {cy4.x, cy4.y, cy4.z, cy4.w};

    float* outb = out + (size_t)b * (32 * HW) + pos;
    const float2* __restrict__ tab2 = reinterpret_cast<const float2*>(table);

    #pragma unroll
    for (int k = 0; k < 3; ++k) {
        const int   l   = 13 + k;
        const float n   = (float)NS3[k];
        const float inv = 1.0f / n;
        const float rcp = 1.0f / inv;
        const float2* __restrict__ tabl = tab2 + (size_t)l * TSIZE;

        float o0[4], o1[4];
        #pragma unroll
        for (int p = 0; p < 4; ++p) {
            const float cx = cxa[p], cy = cya[p];
            const int hx = (int)(cx * n);
            const int hy = (int)(cy * n);
            const float bx = floorf(cx * rcp);
            const float by = floorf(cy * rcp);

            const unsigned hyp0 = (unsigned)hy * PRIME2;
            const unsigned hyp1 = (unsigned)(hy + 1) * PRIME2;
            const float2 f00 = tabl[((unsigned)hx       ^ hyp0) & HMASK];
            const float2 f10 = tabl[((unsigned)(hx + 1) ^ hyp0) & HMASK];
            const float2 f01 = tabl[((unsigned)hx       ^ hyp1) & HMASK];
            const float2 f11 = tabl[((unsigned)(hx + 1) ^ hyp1) & HMASK];

            const float wx_lo = ((bx + 1.0f) * inv - cx) * n;
            const float wx_hi = (cx - bx * inv) * n;
            const float wy_lo = ((by + 1.0f) * inv - cy) * n;
            const float wy_hi = (cy - by * inv) * n;

            const float r1x = f00.x * wx_lo + f10.x * wx_hi;
            const float r1y = f00.y * wx_lo + f10.y * wx_hi;
            const float r2x = f01.x * wx_lo + f11.x * wx_hi;
            const float r2y = f01.y * wx_lo + f11.y * wx_hi;
            o0[p] = r1x * wy_lo + r2x * wy_hi;
            o1[p] = r1y * wy_lo + r2y * wy_hi;
        }
        f4 v0 = {o0[0], o0[1], o0[2], o0[3]};
        f4 v1 = {o1[0], o1[1], o1[2], o1[3]};
        __builtin_nontemporal_store(v0, (f4*)(outb + (size_t)(2 * l)     * HW));
        __builtin_nontemporal_store(v1, (f4*)(outb + (size_t)(2 * l + 1) * HW));
    }
}

__global__ __launch_bounds__(BLKB)
void hashenc_lds(const float* __restrict__ coord,
                 const float* __restrict__ table,
                 float* __restrict__ out)
{
    constexpr int NS[13]  = {8, 9, 11, 13, 16, 20, 24, 29, 35, 42, 50, 61, 73};
    constexpr int OFF[13] = {0, 100, 221, 390, 615, 939, 1423, 2099, 3060, 4429,
                             6365, 9069, 13038};

    extern __shared__ float2 smem[];   // 18663 float2 = 149,304 B

    const float2* __restrict__ tab2 = reinterpret_cast<const float2*>(table);

    // ---- stage levels 0..12 as dense (n+2)^2 de-hashed grids ----
    #pragma unroll
    for (int l = 0; l < NLEV_LDS; ++l) {
        const int W  = NS[l] + 2;
        const int SZ = W * W;
        const float2* __restrict__ tabl = tab2 + (size_t)l * TSIZE;
        for (int e = threadIdx.x; e < SZ; e += BLKB) {
            const int j = e / W;              // W constexpr after unroll
            const int i = e - j * W;
            const unsigned idx = ((unsigned)i ^ ((unsigned)j * PRIME2)) & HMASK;
            smem[OFF[l] + e] = tabl[idx];
        }
    }

    const int g   = blockIdx.x * BLKB + threadIdx.x;  // 0..262143
    const int P   = g << 2;
    const int b   = P >> 18;
    const int pos = P & (HW - 1);

    const float* cbase = coord + (size_t)b * (2 * HW);
    const float4 cx4 = *reinterpret_cast<const float4*>(cbase + pos);
    const float4 cy4 = *reinterpret_cast<const float4*>(cbase + HW + pos);
    const float cxa[4] = {cx4.x, cx4.y, cx4.z, cx4.w};
    const float cya[4] = {cy4.x, cy4.y, cy4.z, cy4.w};

    float* outb = out + (size_t)b * (32 * HW) + pos;

    __syncthreads();

    #pragma unroll
    for (int l = 0; l < NLEV_LDS; ++l) {
        const float n   = (float)NS[l];
        const float inv = 1.0f / n;
        const float rcp = 1.0f / inv;
        const int   W   = NS[l] + 2;
        const float2* __restrict__ sl = smem + OFF[l];

        float o0[4], o1[4];
        #pragma unroll
        for (int p = 0; p < 4; ++p) {
            const float cx = cxa[p], cy = cya[p];
            const int hx = (int)(cx * n);
            const int hy = (int)(cy * n);
            const float bx = floorf(cx * rcp);
            const float by = floorf(cy * rcp);

            const int base = hy * W + hx;
            const float2 f00 = sl[base];
            const float2 f10 = sl[base + 1];
            const float2 f01 = sl[base + W];
            const float2 f11 = sl[base + W + 1];

            const float wx_lo = ((bx + 1.0f) * inv - cx) * n;
            const float wx_hi = (cx - bx * inv) * n;
            const float wy_lo = ((by + 1.0f) * inv - cy) * n;
            const float wy_hi = (cy - by * inv) * n;

            const float r1x = f00.x * wx_lo + f10.x * wx_hi;
            const float r1y = f00.y * wx_lo + f10.y * wx_hi;
            const float r2x = f01.x * wx_lo + f11.x * wx_hi;
            const float r2y = f01.y * wx_lo + f11.y * wx_hi;
            o0[p] = r1x * wy_lo + r2x * wy_hi;
            o1[p] = r1y * wy_lo + r2y * wy_hi;
        }
        f4 v0 = {o0[0], o0[1], o0[2], o0[3]};
        f4 v1 = {o1[0], o1[1], o1[2], o1[3]};
        __builtin_nontemporal_store(v0, (f4*)(outb + (size_t)(2 * l)     * HW));
        __builtin_nontemporal_store(v1, (f4*)(outb + (size_t)(2 * l + 1) * HW));
    }
}

extern "C" void kernel_launch(void* const* d_in, const int* in_sizes, int n_in,
                              void* d_out, int out_size, void* d_ws, size_t ws_size,
                              hipStream_t stream) {
    const float* coord = (const float*)d_in[0];
    const float* table = (const float*)d_in[1];
    if (n_in >= 2 && in_sizes[0] > in_sizes[1]) {   // size-based disambiguation
        coord = (const float*)d_in[1];
        table = (const float*)d_in[0];
    }
    float* out = (float*)d_out;

    // 149,304 B dynamic LDS: opt in above the 64KB default cap (host-side,
    // idempotent, graph-capture safe).
    (void)hipFuncSetAttribute((const void*)hashenc_lds,
                              hipFuncAttributeMaxDynamicSharedMemorySize,
                              (int)(LDS_TOT * sizeof(float2)));

    // A: levels 13-15, 1M px / (256 thr * 4 px) = 1024 blocks, no LDS.
    hashenc_direct<<<1024, 256, 0, stream>>>(coord, table, out);
    // B: levels 0-12, 1M px / (1024 thr * 4 px) = 256 blocks, 149KB LDS.
    hashenc_lds<<<256, BLKB, LDS_TOT * sizeof(float2), stream>>>(coord, table, out);
}

// Round 11
// 47.928 us; speedup vs baseline: 1.9411x; 1.2037x over previous
//
#include <hip/hip_runtime.h>

#define HW 262144            // 512*512
#define TSIZE 524288         // 2^19 entries per level
#define HMASK 524287u
#define PRIME2 2654435761u
#define NLEV_LDS 13          // levels 0..12 staged (n <= 73)
#define LDS_TOT 18663        // sum of (NS[l]+2)^2 for l<13, float2 = 149,304 B
#define BLK 1024
#define PPT 2                // pixels per thread

typedef float f2v __attribute__((ext_vector_type(2)));

// Reference semantics (locked R1-R7): JAX/XLA f32:
//   hx = int32(fl32(cx*n)); bx = floorf(fl32(cx*rcp)), rcp = fl32(1/fl32(1/n));
//   NS[15] = 127.
// Ladder: R7 93us (direct) -> R8 70 (10 staged) -> R9 67 (12 staged fused)
// -> R10 57.7 (split kernels, 13 staged, NT stores).
// R11: re-fuse with gathers issued AFTER the barrier so the 12M direct probes'
// line-throughput overlaps the 13 LDS levels' VALU work (R9 failed because
// pre-barrier gathers drain at the barrier's vmcnt(0)).
__global__ __launch_bounds__(BLK)
void hashenc_fused(const float* __restrict__ coord,
                   const float* __restrict__ table,
                   float* __restrict__ out)
{
    constexpr int NS[13]  = {8, 9, 11, 13, 16, 20, 24, 29, 35, 42, 50, 61, 73};
    constexpr int OFF[13] = {0, 100, 221, 390, 615, 939, 1423, 2099, 3060, 4429,
                             6365, 9069, 13038};
    constexpr int NSD[3]  = {88, 106, 127};   // direct levels 13,14,15

    extern __shared__ float2 smem[];   // 18663 float2 = 149,304 B

    const float2* __restrict__ tab2 = reinterpret_cast<const float2*>(table);

    // ---- stage levels 0..12 as dense (n+2)^2 de-hashed grids ----
    #pragma unroll
    for (int l = 0; l < NLEV_LDS; ++l) {
        const int W  = NS[l] + 2;
        const int SZ = W * W;
        const float2* __restrict__ tabl = tab2 + (size_t)l * TSIZE;
        for (int e = threadIdx.x; e < SZ; e += BLK) {
            const int j = e / W;              // W constexpr after unroll
            const int i = e - j * W;
            const unsigned idx = ((unsigned)i ^ ((unsigned)j * PRIME2)) & HMASK;
            smem[OFF[l] + e] = tabl[idx];
        }
    }

    // ---- per-thread pixel pair ----
    const int g   = blockIdx.x * BLK + threadIdx.x;   // 0..524287
    const int P   = g << 1;                           // first of 2 pixels
    const int b   = P >> 18;                          // batch (HW = 2^18)
    const int pos = P & (HW - 1);

    const float* cbase = coord + (size_t)b * (2 * HW);
    const float2 cxp = *reinterpret_cast<const float2*>(cbase + pos);
    const float2 cyp = *reinterpret_cast<const float2*>(cbase + HW + pos);
    const float cxa[PPT] = {cxp.x, cxp.y};
    const float cya[PPT] = {cyp.x, cyp.y};

    float* outb = out + (size_t)b * (32 * HW) + pos;

    __syncthreads();

    // ---- issue ALL direct-level gathers NOW (post-barrier): their vmcnt
    //      cost runs concurrently with the LDS-level VALU below ----
    float2 gd[3][PPT * 4];
    #pragma unroll
    for (int k = 0; k < 3; ++k) {
        const float n = (float)NSD[k];
        const float2* __restrict__ tabl = tab2 + (size_t)(13 + k) * TSIZE;
        #pragma unroll
        for (int p = 0; p < PPT; ++p) {
            const int hx = (int)(cxa[p] * n);
            const int hy = (int)(cya[p] * n);
            const unsigned hyp0 = (unsigned)hy * PRIME2;
            const unsigned hyp1 = (unsigned)(hy + 1) * PRIME2;
            gd[k][p * 4 + 0] = tabl[((unsigned)hx       ^ hyp0) & HMASK];
            gd[k][p * 4 + 1] = tabl[((unsigned)(hx + 1) ^ hyp0) & HMASK];
            gd[k][p * 4 + 2] = tabl[((unsigned)hx       ^ hyp1) & HMASK];
            gd[k][p * 4 + 3] = tabl[((unsigned)(hx + 1) ^ hyp1) & HMASK];
        }
    }

    // ---- staged levels 0..12 from LDS (lgkmcnt pipe; vmcnt loads in flight) ----
    #pragma unroll
    for (int l = 0; l < NLEV_LDS; ++l) {
        const float n   = (float)NS[l];
        const float inv = 1.0f / n;
        const float rcp = 1.0f / inv;
        const int   W   = NS[l] + 2;
        const float2* __restrict__ sl = smem + OFF[l];

        float o0[PPT], o1[PPT];
        #pragma unroll
        for (int p = 0; p < PPT; ++p) {
            const float cx = cxa[p], cy = cya[p];
            const int hx = (int)(cx * n);
            const int hy = (int)(cy * n);
            const float bx = floorf(cx * rcp);
            const float by = floorf(cy * rcp);

            const int base = hy * W + hx;
            const float2 f00 = sl[base];
            const float2 f10 = sl[base + 1];
            const float2 f01 = sl[base + W];
            const float2 f11 = sl[base + W + 1];

            const float wx_lo = ((bx + 1.0f) * inv - cx) * n;
            const float wx_hi = (cx - bx * inv) * n;
            const float wy_lo = ((by + 1.0f) * inv - cy) * n;
            const float wy_hi = (cy - by * inv) * n;

            const float r1x = f00.x * wx_lo + f10.x * wx_hi;
            const float r1y = f00.y * wx_lo + f10.y * wx_hi;
            const float r2x = f01.x * wx_lo + f11.x * wx_hi;
            const float r2y = f01.y * wx_lo + f11.y * wx_hi;
            o0[p] = r1x * wy_lo + r2x * wy_hi;
            o1[p] = r1y * wy_lo + r2y * wy_hi;
        }
        f2v v0 = {o0[0], o0[1]};
        f2v v1 = {o1[0], o1[1]};
        __builtin_nontemporal_store(v0, (f2v*)(outb + (size_t)(2 * l)     * HW));
        __builtin_nontemporal_store(v1, (f2v*)(outb + (size_t)(2 * l + 1) * HW));
    }

    // ---- direct levels 13..15: blend the (long-landed) gathers ----
    #pragma unroll
    for (int k = 0; k < 3; ++k) {
        const int   l   = 13 + k;
        const float n   = (float)NSD[k];
        const float inv = 1.0f / n;
        const float rcp = 1.0f / inv;

        float o0[PPT], o1[PPT];
        #pragma unroll
        for (int p = 0; p < PPT; ++p) {
            const float cx = cxa[p], cy = cya[p];
            const float bx = floorf(cx * rcp);
            const float by = floorf(cy * rcp);

            const float2 f00 = gd[k][p * 4 + 0];
            const float2 f10 = gd[k][p * 4 + 1];
            const float2 f01 = gd[k][p * 4 + 2];
            const float2 f11 = gd[k][p * 4 + 3];

            const float wx_lo = ((bx + 1.0f) * inv - cx) * n;
            const float wx_hi = (cx - bx * inv) * n;
            const float wy_lo = ((by + 1.0f) * inv - cy) * n;
            const float wy_hi = (cy - by * inv) * n;

            const float r1x = f00.x * wx_lo + f10.x * wx_hi;
            const float r1y = f00.y * wx_lo + f10.y * wx_hi;
            const float r2x = f01.x * wx_lo + f11.x * wx_hi;
            const float r2y = f01.y * wx_lo + f11.y * wx_hi;
            o0[p] = r1x * wy_lo + r2x * wy_hi;
            o1[p] = r1y * wy_lo + r2y * wy_hi;
        }
        f2v v0 = {o0[0], o0[1]};
        f2v v1 = {o1[0], o1[1]};
        __builtin_nontemporal_store(v0, (f2v*)(outb + (size_t)(2 * l)     * HW));
        __builtin_nontemporal_store(v1, (f2v*)(outb + (size_t)(2 * l + 1) * HW));
    }
}

extern "C" void kernel_launch(void* const* d_in, const int* in_sizes, int n_in,
                              void* d_out, int out_size, void* d_ws, size_t ws_size,
                              hipStream_t stream) {
    const float* coord = (const float*)d_in[0];
    const float* table = (const float*)d_in[1];
    if (n_in >= 2 && in_sizes[0] > in_sizes[1]) {   // size-based disambiguation
        coord = (const float*)d_in[1];
        table = (const float*)d_in[0];
    }
    float* out = (float*)d_out;

    // 149,304 B dynamic LDS: opt in above the 64KB default cap (host-side,
    // idempotent, graph-capture safe).
    (void)hipFuncSetAttribute((const void*)hashenc_fused,
                              hipFuncAttributeMaxDynamicSharedMemorySize,
                              (int)(LDS_TOT * sizeof(float2)));

    // 1M pixels / (1024 thr * 2 px) = 512 blocks, 149KB LDS, 1 block/CU.
    hashenc_fused<<<512, BLK, LDS_TOT * sizeof(float2), stream>>>(coord, table, out);
}